// Round 6
// baseline (270.108 us; speedup 1.0000x reference)
//
#include <hip/hip_runtime.h>
#include <math.h>

// TrimSilence: WIN=32000, HOP=4000, OFF=8000, K=256, SEG=16000, T=40e6 @ f32.
//
// Round-6 theory: the reference ranking was produced by JAX on TPU, where
// jnp.cumsum lowers to reduce_window and XLA's ReduceWindowRewriter
// (base_length=16) turns it into a recursive radix-16 two-phase scan:
//   level0: 10000 = 625 blocks x16, sequential scan within each block,
//   level1: 625 block-sums = 39x16+1, same treatment,
//   level2: 40 = 2x16+8,  level3: 3 -> plain sequential scan.
//   combine downward: cs[16b+j] = fl( P_b + inner[b][j] ), P_0 = 0.
// Block-sum TREE is provably irrelevant (r1/r2/r4 gave identical results);
// only the cumsum association matters. means=(bc[i+8]-bc[i])/32000 (f32),
// exact top-256 (ties -> lowest index), centers ascending, linspace fade.

#define T_LEN  40000000
#define HOP    4000
#define NBLK   10000      // T/HOP
#define NWIN   9993       // (T-WIN)/HOP + 1
#define KSEL   256
#define SEG    16000
#define OFF    8000

// ---- K1: per-4000-block |x| sums (tree-agnostic, fast) ---------------------
__global__ __launch_bounds__(256) void k_blocksums(const float* __restrict__ in,
                                                   float* __restrict__ blocks) {
    const int half = threadIdx.x >> 5;             // 8 half-waves per block
    const int j    = threadIdx.x & 31;
    const int row  = blockIdx.x * 8 + half;        // 0..9999
    const float* p = in + (size_t)row * 4000 + j;
    float acc = 0.0f;
    #pragma unroll 5
    for (int i = 0; i < 125; ++i) acc += fabsf(p[i * 32]);
    acc += __shfl_xor(acc, 16);
    acc += __shfl_xor(acc, 8);
    acc += __shfl_xor(acc, 4);
    acc += __shfl_xor(acc, 2);
    acc += __shfl_xor(acc, 1);
    if (j == 0) blocks[row] = acc;
}

// ---- K2: radix-16 two-phase cumsum, f32 means, top-256, ordered compact ----
__global__ __launch_bounds__(1024) void k_select(const float* __restrict__ blocks,
                                                 unsigned* __restrict__ um,
                                                 int* __restrict__ sel) {
    __shared__ float sb[NBLK];     // x -> inner0 scans -> cs (all in place)
    __shared__ float s0[625];      // level-0 block sums
    __shared__ float w1[640];      // level-1 inner scans
    __shared__ float s1[40];       // level-1 block sums
    __shared__ float w2[48];       // level-2 inner scans
    __shared__ float s2[3];        // level-2 block sums
    __shared__ float p3[3];        // level-3 exclusive scan
    __shared__ float p2s[40];      // scan of s1 (level-2 combined)
    __shared__ float p1s[625];     // scan of s0 (level-1 combined)
    __shared__ unsigned hist[256];
    __shared__ unsigned sc[1024];
    __shared__ unsigned sc2[1024];
    __shared__ unsigned s_pfx, s_k;
    const int tid = threadIdx.x;

    for (int i = tid; i < NBLK; i += 1024) sb[i] = blocks[i];
    __syncthreads();

    // level-0 inner: sequential scan within each 16-block (in place)
    if (tid < 625) {
        const int base = tid * 16;
        float s = sb[base];
        #pragma unroll
        for (int j = 1; j < 16; ++j) { s += sb[base + j]; sb[base + j] = s; }
        s0[tid] = s;
    }
    __syncthreads();
    // level-1 inner: sequential scan of s0 within 16-blocks (block 39: 1 elem)
    if (tid < 40) {
        const int base = tid * 16;
        const int cnt  = (tid == 39) ? 1 : 16;
        float s = s0[base];
        w1[base] = s;
        for (int j = 1; j < cnt; ++j) { s += s0[base + j]; w1[base + j] = s; }
        s1[tid] = s;
    }
    __syncthreads();
    // level-2 inner: sequential scan of s1 within 16-blocks (block 2: 8 elems)
    if (tid < 3) {
        const int base = tid * 16;
        const int cnt  = (tid == 2) ? 8 : 16;
        float s = s1[base];
        w2[base] = s;
        for (int j = 1; j < cnt; ++j) { s += s1[base + j]; w2[base + j] = s; }
        s2[tid] = s;
    }
    __syncthreads();
    // level-3: sequential scan of 3, exclusive
    if (tid == 0) {
        p3[0] = 0.0f;
        p3[1] = s2[0];
        p3[2] = s2[0] + s2[1];
        s_pfx = 0u; s_k = KSEL;
    }
    __syncthreads();
    // combine level-2: scan2[16d+j] = P3[d] + inner2[d][j]  (fl(0+x)==x)
    if (tid < 40) p2s[tid] = p3[tid >> 4] + w2[tid];
    __syncthreads();
    // combine level-1: scan1[16c+j] = P2[c] + inner1[c][j], P2[0]=0
    if (tid < 625) {
        const int c = tid >> 4;
        const float P2 = (c == 0) ? 0.0f : p2s[c - 1];
        p1s[tid] = P2 + w1[tid];
    }
    __syncthreads();
    // combine level-0: cs[16b+j] = P1[b] + inner0[b][j], P1[0]=0 (in place)
    for (int i = tid; i < NBLK; i += 1024) {
        const int b = i >> 4;
        const float P1 = (b == 0) ? 0.0f : p1s[b - 1];
        sb[i] = P1 + sb[i];
    }
    __syncthreads();
    // means[i] = (bc[i+8]-bc[i])/32000 = (cs[i+7]-cs[i-1])/32000, cs[-1]=0
    for (int i = tid; i < NWIN; i += 1024) {
        const float lo = (i == 0) ? 0.0f : sb[i - 1];
        const float m = (sb[i + 7] - lo) / 32000.0f;
        um[i] = __float_as_uint(m);      // positive f32 -> orderable uint
    }
    __syncthreads();

    // 4-pass 8-bit radix select for the 256th-largest value C
    for (int pass = 0; pass < 4; ++pass) {
        const int shift = 24 - pass * 8;
        if (tid < 256) hist[tid] = 0u;
        __syncthreads();
        const unsigned pfx = s_pfx;
        const unsigned kcur = s_k;
        for (int i = tid; i < NWIN; i += 1024) {
            unsigned u = um[i];
            bool cand = (pass == 0) || ((u >> (shift + 8)) == pfx);
            if (cand) atomicAdd(&hist[(u >> shift) & 255u], 1u);
        }
        __syncthreads();
        if (tid < 256) {
            unsigned suf = 0;                 // candidates in bins >= tid
            for (int jj = tid; jj < 256; ++jj) suf += hist[jj];
            unsigned above = suf - hist[tid]; // strictly higher bins
            if (suf >= kcur && above < kcur) {  // exactly one tid matches
                s_pfx = (pfx << 8) | (unsigned)tid;
                s_k = kcur - above;
            }
        }
        __syncthreads();
    }
    const unsigned C   = s_pfx;   // 256th-largest mean (bits)
    const unsigned keq = s_k;     // how many ==C to keep (lowest index first)

    // ordered compaction; each thread owns 10 consecutive indices
    const int lo = tid * 10;
    const int hi = (lo + 10 < NWIN) ? lo + 10 : NWIN;
    unsigned ceq = 0, cgt = 0;
    for (int i = lo; i < hi; ++i) {
        unsigned u = um[i];
        cgt += (u > C) ? 1u : 0u;
        ceq += (u == C) ? 1u : 0u;
    }
    sc[tid] = ceq; sc2[tid] = cgt;
    __syncthreads();
    for (int ofs = 1; ofs < 1024; ofs <<= 1) {   // inclusive Hillis-Steele scan
        unsigned av = 0, bv = 0;
        if (tid >= ofs) { av = sc[tid - ofs]; bv = sc2[tid - ofs]; }
        __syncthreads();
        if (tid >= ofs) { sc[tid] += av; sc2[tid] += bv; }
        __syncthreads();
    }
    unsigned e = sc[tid]  - ceq;   // #eq strictly before my range
    unsigned g = sc2[tid] - cgt;   // #gt strictly before my range
    for (int i = lo; i < hi; ++i) {
        unsigned u = um[i];
        if (u > C) {
            unsigned esel = (e < keq) ? e : keq;
            sel[g + esel] = i;     // slot = #selected before i -> ascending idx
            ++g;
        } else if (u == C) {
            if (e < keq) sel[g + e] = i;
            ++e;
        }
    }
}

// ---- K3: gather 256 segments x 16000, apply linspace fade mask -------------
__global__ __launch_bounds__(256) void k_gather(const float* __restrict__ in,
                                                const int* __restrict__ sel,
                                                float* __restrict__ out) {
    const int b = blockIdx.x;
    const int s = b >> 2;          // segment 0..255
    const int part = b & 3;        // quarter of the segment
    const int w = sel[s];          // window index (ascending across s)
    const float4* ip = (const float4*)(in + (size_t)w * HOP + OFF);
    float4* op = (float4*)(out + (size_t)s * SEG);
    const double st = 1.0 / 15999.0;   // np.linspace step (f64), last elem = 1
    const int v0 = part * 1000;
    for (int v = v0 + threadIdx.x; v < v0 + 1000; v += 256) {
        float4 x = ip[v];
        int jj = v * 4;
        float t0 = (float)(jj * st);
        float t1 = (float)((jj + 1) * st);
        float t2 = (float)((jj + 2) * st);
        float t3 = (jj + 3 == 15999) ? 1.0f : (float)((jj + 3) * st);
        x.x *= t0 * (1.0f - t0);
        x.y *= t1 * (1.0f - t1);
        x.z *= t2 * (1.0f - t2);
        x.w *= t3 * (1.0f - t3);
        op[v] = x;
    }
}

extern "C" void kernel_launch(void* const* d_in, const int* in_sizes, int n_in,
                              void* d_out, int out_size, void* d_ws, size_t ws_size,
                              hipStream_t stream) {
    (void)in_sizes; (void)n_in; (void)out_size; (void)ws_size;
    const float* in = (const float*)d_in[0];
    float* out = (float*)d_out;
    char* ws = (char*)d_ws;
    float*    blocks = (float*)ws;                 // 10000 f32 @ 0
    unsigned* um     = (unsigned*)(ws + 40960);    // 9993  u32
    int*      sel    = (int*)(ws + 81920);         // 256   i32
    k_blocksums<<<dim3(NBLK / 8), dim3(256), 0, stream>>>(in, blocks);
    k_select<<<dim3(1), dim3(1024), 0, stream>>>(blocks, um, sel);
    k_gather<<<dim3(KSEL * 4), dim3(256), 0, stream>>>(in, sel, out);
}